// Round 6
// baseline (674.652 us; speedup 1.0000x reference)
//
#include <hip/hip_runtime.h>
#include <cstdint>

typedef unsigned short u16;
typedef __attribute__((ext_vector_type(8))) short bf16x8;
typedef __attribute__((ext_vector_type(4))) float f32x4;

__device__ __forceinline__ u16 f2b(float f) {
  union { float f; unsigned u; } c; c.f = f;
  unsigned u = c.u;
  return (u16)((u + 0x7FFFu + ((u >> 16) & 1u)) >> 16);
}
__device__ __forceinline__ float b2f(u16 b) {
  union { unsigned u; float f; } c; c.u = ((unsigned)b) << 16;
  return c.f;
}

typedef __attribute__((address_space(1))) void gv_t;
typedef __attribute__((address_space(3))) void lv_t;
__device__ __forceinline__ void gload_lds16(const void* g, void* l) {
  __builtin_amdgcn_global_load_lds((gv_t*)g, (lv_t*)l, 16, 0, 0);
}

// ---------------------------------------------------------------------------
// Transpose + fp32->bf16 convert: out[c][r] = bf16(in[r][c]); in is R x C.
// block (32,8), grid (C/32, R/32)
// ---------------------------------------------------------------------------
__global__ void transpose_f2b(const float* __restrict__ in, u16* __restrict__ out,
                              int R, int C) {
  __shared__ float t[32][33];
  const int c0 = blockIdx.x * 32, r0 = blockIdx.y * 32;
  const int tx = threadIdx.x, ty = threadIdx.y;
#pragma unroll
  for (int i = 0; i < 4; ++i)
    t[ty + 8 * i][tx] = in[(size_t)(r0 + ty + 8 * i) * C + c0 + tx];
  __syncthreads();
#pragma unroll
  for (int i = 0; i < 4; ++i)
    out[(size_t)(c0 + ty + 8 * i) * R + r0 + tx] = f2b(t[tx][ty + 8 * i]);
}

// ---------------------------------------------------------------------------
// RMSNorm: one row (1024 fp32) per block of 256 threads; bf16 out.
// ---------------------------------------------------------------------------
__global__ __launch_bounds__(256) void rmsnorm_k(const float* __restrict__ x,
                                                 const float* __restrict__ g,
                                                 u16* __restrict__ out) {
  const int row = blockIdx.x, tid = threadIdx.x;
  const float4 v = ((const float4*)x)[(size_t)row * 256 + tid];
  float ss = v.x * v.x + v.y * v.y + v.z * v.z + v.w * v.w;
#pragma unroll
  for (int off = 1; off < 64; off <<= 1) ss += __shfl_xor(ss, off, 64);
  __shared__ float red[4];
  if ((tid & 63) == 0) red[tid >> 6] = ss;
  __syncthreads();
  const float mean = (red[0] + red[1] + red[2] + red[3]) * (1.0f / 1024.0f);
  const float rinv = 1.0f / sqrtf(mean + 1e-6f);
  const float4 gv = ((const float4*)g)[tid];
  u16* o = out + (size_t)row * 1024 + tid * 4;
  o[0] = f2b(v.x * rinv * gv.x);
  o[1] = f2b(v.y * rinv * gv.y);
  o[2] = f2b(v.z * rinv * gv.z);
  o[3] = f2b(v.w * rinv * gv.w);
}

// ---------------------------------------------------------------------------
// RoPE in-place on fused qkv (row stride 3072): rotates q and k halves.
// ---------------------------------------------------------------------------
__global__ __launch_bounds__(256) void rope_k(u16* __restrict__ qkv) {
  const int i = blockIdx.x * 256 + threadIdx.x;   // B*T*NH*32 total
  const int d = i & 31;
  const int h = (i >> 5) & 15;
  const int bt = i >> 9;
  const int t = bt & 2047;
  const float inv = exp2f((float)d * -0.4152410118609203f);  // 10000^(-d/32)
  const float th = (float)t * inv;
  float s, c;
  sincosf(th, &s, &c);
  size_t base = (size_t)bt * 3072 + h * 64 + d;
#pragma unroll
  for (int half = 0; half < 2; ++half) {   // q then k
    const float x1 = b2f(qkv[base]);
    const float x2 = b2f(qkv[base + 32]);
    qkv[base]      = f2b(x1 * c - x2 * s);
    qkv[base + 32] = f2b(x2 * c + x1 * s);
    base += 1024;
  }
}

// ---------------------------------------------------------------------------
// V transpose: qkv (col offset 2048, stride 3072) -> VT (b,h,d,t), u16.
// block (32,8); grid (T/32, 2*B*NH)
// ---------------------------------------------------------------------------
__global__ void vtrans_k(const u16* __restrict__ qkv, u16* __restrict__ VT) {
  __shared__ u16 tl[32][34];
  const int t0 = blockIdx.x * 32;
  const int bh = blockIdx.y >> 1;
  const int d0 = (blockIdx.y & 1) * 32;
  const int b = bh >> 4, h = bh & 15;
  const int tx = threadIdx.x, ty = threadIdx.y;
  const u16* src = qkv + (size_t)(b * 2048 + t0) * 3072 + 2048 + h * 64 + d0;
#pragma unroll
  for (int i = 0; i < 4; ++i)
    tl[ty + 8 * i][tx] = src[(size_t)(ty + 8 * i) * 3072 + tx];
  __syncthreads();
  u16* dst = VT + ((size_t)bh * 64 + d0) * 2048 + t0;
#pragma unroll
  for (int i = 0; i < 4; ++i)
    dst[(size_t)(ty + 8 * i) * 2048 + tx] = tl[tx][ty + 8 * i];
}

// ---------------------------------------------------------------------------
// GEMM: 128x128 tile, BK=32, 256 thr (m97-class 2-barrier). Retained unused
// as fallback reference.
// ---------------------------------------------------------------------------
template <int EPI>
__global__ __launch_bounds__(256)
void gemm_bt(const u16* __restrict__ A, const u16* __restrict__ BT,
             void* __restrict__ Cout, const float* __restrict__ resid,
             int M, int N, int K, int lda) {
  __shared__ alignas(16) u16 As[128 * 32];
  __shared__ alignas(16) u16 Bs[128 * 32];
  const int tid = threadIdx.x;
  const int wave = tid >> 6, lane = tid & 63;
  const int wr = wave >> 1, wc = wave & 1;
  const int l15 = lane & 15, quad = lane >> 4;
  const int bm = blockIdx.x * 128, bn = blockIdx.y * 128;

  f32x4 acc[4][4];
#pragma unroll
  for (int i = 0; i < 4; ++i)
#pragma unroll
    for (int j = 0; j < 4; ++j) acc[i][j] = (f32x4){0.f, 0.f, 0.f, 0.f};

  const int srow = wave * 32 + (lane >> 2);
  const int scol = (lane & 3) * 8;
  const u16* gA0 = A + (size_t)(bm + srow) * lda + scol;
  const u16* gA1 = gA0 + (size_t)16 * lda;
  const u16* gB0 = BT + (size_t)(bn + srow) * K + scol;
  const u16* gB1 = gB0 + (size_t)16 * K;
  u16* lA0 = As + wave * 1024; u16* lA1 = lA0 + 512;
  u16* lB0 = Bs + wave * 1024; u16* lB1 = lB0 + 512;

  const u16* pa = As + (wr * 64 + l15) * 32 + quad * 8;
  const u16* pb = Bs + (wc * 64 + l15) * 32 + quad * 8;

  for (int kt = 0; kt < K; kt += 32) {
    gload_lds16(gA0 + kt, lA0);
    gload_lds16(gA1 + kt, lA1);
    gload_lds16(gB0 + kt, lB0);
    gload_lds16(gB1 + kt, lB1);
    __syncthreads();
    bf16x8 af[4], bfv[4];
#pragma unroll
    for (int i = 0; i < 4; ++i) af[i] = *(const bf16x8*)(pa + i * 512);
#pragma unroll
    for (int j = 0; j < 4; ++j) bfv[j] = *(const bf16x8*)(pb + j * 512);
#pragma unroll
    for (int i = 0; i < 4; ++i)
#pragma unroll
      for (int j = 0; j < 4; ++j)
        acc[i][j] = __builtin_amdgcn_mfma_f32_16x16x32_bf16(af[i], bfv[j], acc[i][j], 0, 0, 0);
    __syncthreads();
  }

#pragma unroll
  for (int i = 0; i < 4; ++i) {
    const int gr = bm + wr * 64 + i * 16 + quad * 4;
#pragma unroll
    for (int j = 0; j < 4; ++j) {
      const int gc = bn + wc * 64 + j * 16 + l15;
#pragma unroll
      for (int r = 0; r < 4; ++r) {
        const size_t off = (size_t)(gr + r) * N + gc;
        if (EPI == 0) {
          ((u16*)Cout)[off] = f2b(acc[i][j][r]);
        } else {
          ((float*)Cout)[off] = resid[off] + acc[i][j][r];
        }
      }
    }
  }
}

// ---------------------------------------------------------------------------
// GEMM 256x256, 2-phase-per-K-tile deep pipeline (v2 of the 8-phase port).
//   Round-5 PMC showed the 4-phase variant re-read B half-tiles (32
//   ds_read_b128/wave/tile) -> LDS-read burst > MFMA burst, MfmaUtil 38%.
//   v2 widens B regs to b[4][2] (all 4 n-frags) -> 24 reads/tile, 2 barrier
//   pairs/tile, 32-MFMA clusters.
//   Phase A(t): reads {A0,B0,B1}(t), stages A1(t+1) [2 loads].
//   Phase B(t): reads {A1}(t),       stages {A0,B0,B1}(t+2) [6 loads].
//   vmcnt ledger (outstanding-after-needed-unit): uniform vmcnt(8) at every
//   steady boundary; tail: A(NT-1)->vmcnt(0), B(NT-2)->vmcnt(2). Every LDS
//   slot overwrite stays barrier-separated from its last reader.
//   Requires M%256==0, N%256==0, K%64==0, NT>=2.
// ---------------------------------------------------------------------------
template <int EPI>
__global__ __launch_bounds__(512, 2)
void gemm256(const u16* __restrict__ A, const u16* __restrict__ BT,
             void* __restrict__ Cout, const float* __restrict__ resid,
             int M, int N, int K, int lda) {
  __shared__ alignas(16) u16 LDS[65536];   // 128 KiB: A [0,64K), B [64K,128K)
  char* const ldsc = (char*)LDS;
  const int tid = threadIdx.x;
  const int wave = tid >> 6, lane = tid & 63;
  const int wr = wave >> 2, wc = wave & 3;        // 2 x 4 wave grid
  const int l15 = lane & 15, quad = lane >> 4;
  const int bm = blockIdx.x * 256, bn = blockIdx.y * 256;
  const int NT = K >> 6;                          // 64-wide K tiles

  // swizzled per-lane ds-read byte offsets (buf0, kk0, frag 0)
  const int swz = (l15 & 8) << 2;                 // flip byte bit5 when row&8
  const int aoff = (((wr * 64 + l15) * 64 + quad * 16) ^ swz);
  const int boff = (((wc * 32 + l15) * 64 + quad * 16) ^ swz) + 65536;

  // staging: per-lane global source, k-position inverse-swizzled (rule 21)
  const int kperm = ((lane & 3) ^ ((lane >> 5) << 1)) * 8;
  const u16* sA = A + (size_t)(bm + wave * 16 + (lane >> 2)) * lda + kperm;
  const u16* sB = BT + (size_t)(bn + wave * 16 + (lane >> 2)) * K + kperm;
  const size_t hA = (size_t)128 * lda;            // A half-tile row step
  const size_t hB = (size_t)128 * K;              // B half-tile row step
  const int dstW = wave * 1024;                   // linear 1 KiB per wave-load

  f32x4 acc[8][4];
#pragma unroll
  for (int m = 0; m < 8; ++m)
#pragma unroll
    for (int n = 0; n < 4; ++n) acc[m][n] = (f32x4){0.f, 0.f, 0.f, 0.f};
  bf16x8 a[4][2], b[4][2];

  // slot: 0 = A-h0, 1 = B-h0, 2 = A-h1, 3 = B-h1
#define STAGE(kt_, slot_, buf_)                                               \
  if ((kt_) < NT) {                                                           \
    const u16* s_ = (((slot_) & 1) ? sB + ((size_t)((slot_) >> 1)) * hB       \
                                   : sA + ((size_t)((slot_) >> 1)) * hA) +    \
                    (size_t)(kt_) * 64;                                       \
    char* d_ = ldsc + (((slot_) & 1) ? 65536 : 0) + (buf_) * 32768 +          \
               ((slot_) >> 1) * 16384 + dstW;                                 \
    gload_lds16(s_, d_);                                                      \
    gload_lds16(s_ + 32, d_ + 8192);                                          \
  }

#define LOAD_A(mh_, buf_)                                                     \
  _Pragma("unroll") for (int mf = 0; mf < 4; ++mf)                            \
      _Pragma("unroll") for (int kk = 0; kk < 2; ++kk)                        \
          a[mf][kk] = *(const bf16x8*)(ldsc + aoff + (buf_) * 32768 +         \
                                       (mh_) * 16384 + kk * 8192 + mf * 1024);

#define LOAD_B2(buf_)                                                         \
  _Pragma("unroll") for (int nh = 0; nh < 2; ++nh)                            \
      _Pragma("unroll") for (int nf = 0; nf < 2; ++nf)                        \
          _Pragma("unroll") for (int kk = 0; kk < 2; ++kk)                    \
              b[nh * 2 + nf][kk] =                                            \
                  *(const bf16x8*)(ldsc + boff + (buf_) * 32768 +             \
                                   nh * 16384 + kk * 8192 + nf * 1024);

#define MMA2(mh_)                                                             \
  __builtin_amdgcn_s_setprio(1);                                              \
  _Pragma("unroll") for (int mf = 0; mf < 4; ++mf)                            \
      _Pragma("unroll") for (int n = 0; n < 4; ++n)                           \
          _Pragma("unroll") for (int kk = 0; kk < 2; ++kk)                    \
              acc[(mh_) * 4 + mf][n] =                                        \
                  __builtin_amdgcn_mfma_f32_16x16x32_bf16(                    \
                      a[mf][kk], b[n][kk], acc[(mh_) * 4 + mf][n], 0, 0, 0);  \
  __builtin_amdgcn_s_setprio(0);

#define BAR() __builtin_amdgcn_s_barrier()
#define DRAIN_LGKM()                                                          \
  {                                                                           \
    asm volatile("s_waitcnt lgkmcnt(0)" ::: "memory");                        \
    __builtin_amdgcn_sched_barrier(0);                                        \
  }

  // prologue: U(0)={A0,B0,B1}(t0) [6], A1(t0) [2], U(1) [6] -> wait oldest 6
  STAGE(0, 0, 0); STAGE(0, 1, 0); STAGE(0, 3, 0);
  STAGE(0, 2, 0);
  STAGE(1, 0, 1); STAGE(1, 1, 1); STAGE(1, 3, 1);
  asm volatile("s_waitcnt vmcnt(8)" ::: "memory");  // U(0) landed
  BAR();

  for (int t = 0; t < NT; ++t) {
    const int bsel = t & 1;
    // ---- phase A: reads A0(t), B0(t), B1(t) ----
    LOAD_A(0, bsel); LOAD_B2(bsel);
    STAGE(t + 1, 2, bsel ^ 1);                       // A1(t+1)
    BAR(); DRAIN_LGKM(); MMA2(0);
    if (t == NT - 1) { asm volatile("s_waitcnt vmcnt(0)" ::: "memory"); }
    else             { asm volatile("s_waitcnt vmcnt(8)" ::: "memory"); }
    BAR();                                           // A1(t) landed
    // ---- phase B: reads A1(t) ----
    LOAD_A(1, bsel);
    STAGE(t + 2, 0, bsel); STAGE(t + 2, 1, bsel); STAGE(t + 2, 3, bsel);
    BAR(); DRAIN_LGKM(); MMA2(1);
    if (t < NT - 2) {
      asm volatile("s_waitcnt vmcnt(8)" ::: "memory");
      BAR();                                         // U(t+1) landed
    } else if (t == NT - 2) {
      asm volatile("s_waitcnt vmcnt(2)" ::: "memory");
      BAR();
    }
    // t == NT-1: fall through to epilogue (no LDS reads follow)
  }
#undef STAGE
#undef LOAD_A
#undef LOAD_B2
#undef MMA2

  // epilogue: C/D layout col=lane&15, row=(lane>>4)*4+reg
#pragma unroll
  for (int m = 0; m < 8; ++m) {
    const int gr = bm + (m >> 2) * 128 + wr * 64 + (m & 3) * 16 + quad * 4;
#pragma unroll
    for (int n = 0; n < 4; ++n) {
      const int gc = bn + (n >> 1) * 128 + wc * 32 + (n & 1) * 16 + l15;
#pragma unroll
      for (int r = 0; r < 4; ++r) {
        const size_t off = (size_t)(gr + r) * N + gc;
        if (EPI == 0) {
          ((u16*)Cout)[off] = f2b(acc[m][n][r]);
        } else {
          ((float*)Cout)[off] = resid[off] + acc[m][n][r];
        }
      }
    }
  }
#undef BAR
#undef DRAIN_LGKM
}

// ---------------------------------------------------------------------------
// GEMM 256x128 deep-pipelined (for N=1024: 256 wg = 1/CU). See round-3 notes.
// Requires M%256==0, N%128==0, K%64==0, NT>=3.
// ---------------------------------------------------------------------------
template <int EPI>
__global__ __launch_bounds__(512, 2)
void gemm256n(const u16* __restrict__ A, const u16* __restrict__ BT,
              void* __restrict__ Cout, const float* __restrict__ resid,
              int M, int N, int K, int lda) {
  __shared__ alignas(16) u16 LDS[49152];   // 96 KiB: A [0,64K), B [64K,96K)
  char* const ldsc = (char*)LDS;
  const int tid = threadIdx.x;
  const int wave = tid >> 6, lane = tid & 63;
  const int wr = wave >> 2, wc = wave & 3;        // 2 x 4 wave grid
  const int l15 = lane & 15, quad = lane >> 4;
  const int bm = blockIdx.x * 256, bn = blockIdx.y * 128;
  const int NT = K >> 6;

  // swizzled per-lane ds-read byte offsets (st_16x32: flip byte bit5 on row&8)
  const int swz = (l15 & 8) << 2;
  const int aoff = (((wr * 64 + l15) * 64 + quad * 16) ^ swz);
  const int boff = (((wc * 32 + l15) * 64 + quad * 16) ^ swz) + 65536;

  // staging: per-lane global source, k-position inverse-swizzled
  const int kperm = ((lane & 3) ^ ((lane >> 5) << 1)) * 8;
  const u16* sA = A + (size_t)(bm + wave * 16 + (lane >> 2)) * lda + kperm;
  const u16* sB = BT + (size_t)(bn + wave * 16 + (lane >> 2)) * K + kperm;
  const size_t hA = (size_t)128 * lda;            // A half-tile row step
  const int dstW = wave * 1024;

  f32x4 acc[8][2];
#pragma unroll
  for (int m = 0; m < 8; ++m)
#pragma unroll
    for (int n = 0; n < 2; ++n) acc[m][n] = (f32x4){0.f, 0.f, 0.f, 0.f};
  bf16x8 a[4][2], b[2][2];

  // A layout: [buf:32768][half:16384][kk:8192][128 rows x 64B]
  // B layout: 65536 + [buf:16384][kk:8192][128 rows x 64B]
#define STAGE_A(kt_, half_, buf_)                                             \
  if ((kt_) < NT) {                                                           \
    const u16* s_ = sA + (size_t)(half_) * hA + (size_t)(kt_) * 64;           \
    char* d_ = ldsc + (buf_) * 32768 + (half_) * 16384 + dstW;                \
    gload_lds16(s_, d_);                                                      \
    gload_lds16(s_ + 32, d_ + 8192);                                          \
  }
#define STAGE_B(kt_, buf_)                                                    \
  if ((kt_) < NT) {                                                           \
    const u16* s_ = sB + (size_t)(kt_) * 64;                                  \
    char* d_ = ldsc + 65536 + (buf_) * 16384 + dstW;                          \
    gload_lds16(s_, d_);                                                      \
    gload_lds16(s_ + 32, d_ + 8192);                                          \
  }
#define LOAD_A(mh_, buf_)                                                     \
  _Pragma("unroll") for (int mf = 0; mf < 4; ++mf)                            \
      _Pragma("unroll") for (int kk = 0; kk < 2; ++kk)                        \
          a[mf][kk] = *(const bf16x8*)(ldsc + aoff + (buf_) * 32768 +         \
                                       (mh_) * 16384 + kk * 8192 + mf * 1024);
#define LOAD_B(buf_)                                                          \
  _Pragma("unroll") for (int nf = 0; nf < 2; ++nf)                            \
      _Pragma("unroll") for (int kk = 0; kk < 2; ++kk)                        \
          b[nf][kk] = *(const bf16x8*)(ldsc + boff + (buf_) * 16384 +         \
                                       kk * 8192 + nf * 1024);
#define MMA(mh_)                                                              \
  __builtin_amdgcn_s_setprio(1);                                              \
  _Pragma("unroll") for (int mf = 0; mf < 4; ++mf)                            \
      _Pragma("unroll") for (int nf = 0; nf < 2; ++nf)                        \
          _Pragma("unroll") for (int kk = 0; kk < 2; ++kk)                    \
              acc[(mh_) * 4 + mf][nf] =                                       \
                  __builtin_amdgcn_mfma_f32_16x16x32_bf16(                    \
                      a[mf][kk], b[nf][kk], acc[(mh_) * 4 + mf][nf], 0, 0, 0);\
  __builtin_amdgcn_s_setprio(0);
#define BAR() __builtin_amdgcn_s_barrier()
#define DRAIN_LGKM()                                                          \
  {                                                                           \
    asm volatile("s_waitcnt lgkmcnt(0)" ::: "memory");                        \
    __builtin_amdgcn_sched_barrier(0);                                        \
  }

  // prologue (issue order defines the vmcnt ledger!)
  STAGE_A(0, 0, 0); STAGE_B(0, 0);   // t0.A0B  (4)
  STAGE_A(0, 1, 0);                  // t0.A1   (2)
  STAGE_A(1, 0, 1); STAGE_B(1, 1);   // t1.A0B  (4)
  asm volatile("s_waitcnt vmcnt(6)" ::: "memory");   // t0.A0B landed
  BAR();

  for (int t = 0; t < NT; ++t) {
    const int bsel = t & 1;
    // ---- phase 0: reads A0(t), B(t) ----
    LOAD_A(0, bsel); LOAD_B(bsel);
    STAGE_A(t + 1, 1, bsel ^ 1);                     // (t+1).A1
    BAR(); DRAIN_LGKM(); MMA(0);
    if (t == NT - 1) { asm volatile("s_waitcnt vmcnt(0)" ::: "memory"); }
    else             { asm volatile("s_waitcnt vmcnt(6)" ::: "memory"); }
    BAR();                                           // A1(t) landed
    // ---- phase 1: reads A1(t) ----
    LOAD_A(1, bsel);
    STAGE_A(t + 2, 0, bsel); STAGE_B(t + 2, bsel);   // (t+2).A0B
    BAR(); DRAIN_LGKM(); MMA(1);
    if (t == NT - 2)     { asm volatile("s_waitcnt vmcnt(2)" ::: "memory"); }
    else if (t < NT - 2) { asm volatile("s_waitcnt vmcnt(6)" ::: "memory"); }
    BAR();                                           // A0B(t+1) landed
  }
#undef STAGE_A
#undef STAGE_B
#undef LOAD_A
#undef LOAD_B
#undef MMA
#undef BAR
#undef DRAIN_LGKM

  // epilogue: C/D layout col=lane&15, row=(lane>>4)*4+reg
#pragma unroll
  for (int m = 0; m < 8; ++m) {
    const int gr = bm + (m >> 2) * 128 + wr * 64 + (m & 3) * 16 + quad * 4;
#pragma unroll
    for (int n = 0; n < 2; ++n) {
      const int gc = bn + wc * 32 + n * 16 + l15;
#pragma unroll
      for (int r = 0; r < 4; ++r) {
        const size_t off = (size_t)(gr + r) * N + gc;
        if (EPI == 0) {
          ((u16*)Cout)[off] = f2b(acc[m][n][r]);
        } else {
          ((float*)Cout)[off] = resid[off] + acc[m][n][r];
        }
      }
    }
  }
}

// ---------------------------------------------------------------------------
// Causal flash attention v6 = split-K over the key range (round-4, verified).
// Fixed-bias softmax -> K-tile contributions are order-independent sums, so
// a q-tile's K range splits EXACTLY across blocks: O = (Oa+Ob)/(Sa+Sb).
// ---------------------------------------------------------------------------
__global__ __launch_bounds__(256)
void attn_kernel(const u16* __restrict__ QKV, const u16* __restrict__ VT,
                 u16* __restrict__ O, float* __restrict__ Opart,
                 float* __restrict__ Spart) {
  const int T = 2048, stQ = 3072;
  const int tid = threadIdx.x, wave = tid >> 6, lane = tid & 63;
  const int l15 = lane & 15, quad = lane >> 4;

  // (qt, chunk) from the 27-slot LPT table
  const int xi = (int)blockIdx.x;
  const bool split = (xi < 22);
  const int qt = split ? (15 - (xi >> 1)) : (26 - xi);
  const int chunk = split ? (xi & 1) : 0;
  const int len = split ? (qt + 1) : (2 * qt + 2);   // tiles this block
  const int kt0 = chunk * (qt + 1);
  const int ktEnd = kt0 + len;

  const int qb0 = qt * 128;
  const int bh = blockIdx.y, b = bh >> 4, h = bh & 15;
  const float sc2 = 0.125f * 1.44269504088896f;   // scale * log2(e)
  const float M0 = 32.0f;                         // fixed softmax bias

  __shared__ alignas(16) u16 Kf[2][8 * 512];  // dbuf, fragment-major
  __shared__ alignas(16) u16 Vf[2][8 * 512];
  __shared__ alignas(16) u16 Pl[4][2][16 * 72];

  const u16* Qb  = QKV + (size_t)b * T * stQ + h * 64;
  const u16* Kb  = Qb + 1024;
  const u16* VTb = VT + (size_t)bh * 64 * T;

  const int r0 = qb0 + wave * 16;   // frag0 wave rows
  const int r1 = r0 + 64;           // frag1 wave rows (always causally active)
  const u16* qp0 = Qb + (size_t)(r0 + l15) * stQ + quad * 8;
  const u16* qp1 = Qb + (size_t)(r1 + l15) * stQ + quad * 8;
  const bf16x8 qf00 = *(const bf16x8*)qp0;
  const bf16x8 qf01 = *(const bf16x8*)(qp0 + 32);
  const bf16x8 qf10 = *(const bf16x8*)qp1;
  const bf16x8 qf11 = *(const bf16x8*)(qp1 + 32);

  bf16x8 ones;
#pragma unroll
  for (int j = 0; j < 8; ++j) ones[j] = (short)0x3F80;   // bf16 1.0

  // staging sources (lane-permuted so LDS lands fragment-major)
  const u16* kS = Kb + (size_t)(wave * 16 + l15) * stQ + quad * 8;
  const u16* vS = VTb + (size_t)(wave * 16 + l15) * T + quad * 8;

  f32x4 o0[4], o1[4], sum0, sum1;
#pragma unroll
  for (int c = 0; c < 4; ++c) {
    o0[c] = (f32x4){0.f, 0.f, 0.f, 0.f};
    o1[c] = (f32x4){0.f, 0.f, 0.f, 0.f};
  }
  sum0 = (f32x4){0.f, 0.f, 0.f, 0.f};
  sum1 = (f32x4){0.f, 0.f, 0.f, 0.f};

  u16* pw0 = &Pl[wave][0][0];
  u16* pw1 = &Pl[wave][1][0];

  // prologue: stage tile kt0 into buf 0
  gload_lds16(kS + (size_t)(kt0 * 64) * stQ,      &Kf[0][(wave * 2 + 0) * 512]);
  gload_lds16(kS + (size_t)(kt0 * 64) * stQ + 32, &Kf[0][(wave * 2 + 1) * 512]);
  gload_lds16(vS + (size_t)(kt0 * 64),            &Vf[0][(wave * 2 + 0) * 512]);
  gload_lds16(vS + (size_t)(kt0 * 64) + 32,       &Vf[0][(wave * 2 + 1) * 512]);

  for (int kt = kt0; kt < ktEnd; ++kt) {
    const int kb0 = kt * 64;
    const int buf = (kt - kt0) & 1;
    __builtin_amdgcn_sched_barrier(0);   // keep stage below prev trailing bar
    if (kt + 1 < ktEnd) {
      const size_t kb1 = (size_t)(kb0 + 64);
      gload_lds16(kS + kb1 * stQ,      &Kf[buf ^ 1][(wave * 2 + 0) * 512]);
      gload_lds16(kS + kb1 * stQ + 32, &Kf[buf ^ 1][(wave * 2 + 1) * 512]);
      gload_lds16(vS + kb1,            &Vf[buf ^ 1][(wave * 2 + 0) * 512]);
      gload_lds16(vS + kb1 + 32,       &Vf[buf ^ 1][(wave * 2 + 1) * 512]);
      asm volatile("s_waitcnt vmcnt(4)" ::: "memory");  // tile kt landed
    } else {
      asm volatile("s_waitcnt vmcnt(0)" ::: "memory");
    }
    __builtin_amdgcn_s_barrier();        // cross-wave visibility of tile kt
    __builtin_amdgcn_sched_barrier(0);   // keep LDS reads below barrier

    bf16x8 kf[8], vf[8];
#pragma unroll
    for (int g = 0; g < 8; ++g) {
      kf[g] = *(const bf16x8*)(&Kf[buf][g * 512 + lane * 8]);
      vf[g] = *(const bf16x8*)(&Vf[buf][g * 512 + lane * 8]);
    }

    const bool act0 = (kb0 <= r0 + 15);   // wave-uniform causal tile skip

    // ---- frag1 (always active): S -> P(bf16, LDS) ----
    {
      f32x4 s[4];
      __builtin_amdgcn_s_setprio(1);
#pragma unroll
      for (int jj = 0; jj < 4; ++jj) {
        s[jj] = (f32x4){0.f, 0.f, 0.f, 0.f};
        s[jj] = __builtin_amdgcn_mfma_f32_16x16x32_bf16(qf10, kf[jj * 2 + 0], s[jj], 0, 0, 0);
        s[jj] = __builtin_amdgcn_mfma_f32_16x16x32_bf16(qf11, kf[jj * 2 + 1], s[jj], 0, 0, 0);
      }
      __builtin_amdgcn_s_setprio(0);
      if (kb0 + 63 > r1) {   // diagonal-crossing tile
#pragma unroll
        for (int jj = 0; jj < 4; ++jj)
#pragma unroll
          for (int r = 0; r < 4; ++r) {
            const bool msk = (kb0 + jj * 16 + l15) > (r1 + quad * 4 + r);
            const float a = msk ? -1e30f : (s[jj][r] * sc2 - M0);
            pw1[(quad * 4 + r) * 72 + jj * 16 + l15] = f2b(exp2f(a));
          }
      } else {
#pragma unroll
        for (int jj = 0; jj < 4; ++jj)
#pragma unroll
          for (int r = 0; r < 4; ++r)
            pw1[(quad * 4 + r) * 72 + jj * 16 + l15] =
                f2b(exp2f(s[jj][r] * sc2 - M0));
      }
    }
    // ---- frag0 (skippable) ----
    if (act0) {
      f32x4 s[4];
      __builtin_amdgcn_s_setprio(1);
#pragma unroll
      for (int jj = 0; jj < 4; ++jj) {
        s[jj] = (f32x4){0.f, 0.f, 0.f, 0.f};
        s[jj] = __builtin_amdgcn_mfma_f32_16x16x32_bf16(qf00, kf[jj * 2 + 0], s[jj], 0, 0, 0);
        s[jj] = __builtin_amdgcn_mfma_f32_16x16x32_bf16(qf01, kf[jj * 2 + 1], s[jj], 0, 0, 0);
      }
      __builtin_amdgcn_s_setprio(0);
      if (kb0 + 63 > r0) {
#pragma unroll
        for (int jj = 0; jj < 4; ++jj)
#pragma unroll
          for (int r = 0; r < 4; ++r) {
            const bool msk = (kb0 + jj * 16 + l15) > (r0 + quad * 4 + r);
            const float a = msk ? -1e30f : (s[jj][r] * sc2 - M0);
            pw0[(quad * 4 + r) * 72 + jj * 16 + l15] = f2b(exp2f(a));
          }
      } else {
#pragma unroll
        for (int jj = 0; jj < 4; ++jj)
#pragma unroll
          for (int r = 0; r < 4; ++r)
            pw0[(quad * 4 + r) * 72 + jj * 16 + l15] =
                f2b(exp2f(s[jj][r] * sc2 - M0));
      }
    }

    // ---- PV + row sums (no rescale needed: fixed bias) ----
    const bf16x8 pf10 = *(const bf16x8*)(pw1 + l15 * 72 + quad * 8);
    const bf16x8 pf11 = *(const bf16x8*)(pw1 + l15 * 72 + 32 + quad * 8);
    __builtin_amdgcn_s_setprio(1);
#pragma unroll
    for (int c = 0; c < 4; ++c) {
      o1[c] = __builtin_amdgcn_mfma_f32_16x16x32_bf16(pf10, vf[c * 2 + 0], o1[c], 0, 0, 0);
      o1[c] = __builtin_amdgcn_mfma_f32_16x16x32_bf16(pf11, vf[c * 2 + 1], o1[c], 0, 0, 0);
    }
    sum1 = __builtin_amdgcn_mfma_f32_16x16x32_bf16(pf10, ones, sum1, 0, 0, 0);
    sum1 = __builtin_amdgcn_mfma_f32_16x16x32_bf16(pf11, ones, sum1, 0, 0, 0);
    __builtin_amdgcn_s_setprio(0);
    if (act0) {
      const bf16x8 pf00 = *(const bf16x8*)(pw0 + l15 * 72 + quad * 8);
      const bf16x8 pf01 = *(const bf16x8*)(pw0 + l15 * 72 + 32 + quad * 8);
      __builtin_amdgcn_s_setprio(1);
#pragma unroll
      for (int c = 0; c < 4; ++c) {
        o0[c] = __builtin_amdgcn_mfma_f32_16x16x32_bf16(pf00, vf[c * 2 + 0], o0[c], 0, 0, 0);
        o0[c] = __builtin_amdgcn_mfma_f32_16x16x32_bf16(pf01, vf[c * 2 + 1], o0[c], 0, 0, 0);
      }
      sum0 = __builtin_amdgcn_mfma_f32_16x16x32_bf16(pf00, ones, sum0, 0, 0, 0);
      sum0 = __builtin_amdgcn_mfma_f32_16x16x32_bf16(pf01, ones, sum0, 0, 0, 0);
      __builtin_amdgcn_s_setprio(0);
    }
    __builtin_amdgcn_s_barrier();        // all waves done reading buf
  }

  if (split) {
    // fp32 partials: Opart[pi][128 rows][64 cols], Spart[pi][128 rows]
    const int pi = (bh * 11 + (qt - 5)) * 2 + chunk;
    float* Po = Opart + (size_t)pi * 8192;
    float* Ps = Spart + (size_t)pi * 128;
    const int lr0 = wave * 16 + quad * 4;     // frag0 local row base
#pragma unroll
    for (int c = 0; c < 4; ++c)
#pragma unroll
      for (int r = 0; r < 4; ++r) {
        Po[(lr0 + r) * 64 + c * 16 + l15]      = o0[c][r];
        Po[(64 + lr0 + r) * 64 + c * 16 + l15] = o1[c][r];
      }
    if (l15 == 0) {
#pragma unroll
      for (int r = 0; r < 4; ++r) {
        Ps[lr0 + r]      = sum0[r];
        Ps[64 + lr0 + r] = sum1[r];
      }
    }
  } else {
    float i0[4], i1[4];
#pragma unroll
    for (int r = 0; r < 4; ++r) { i0[r] = 1.f / sum0[r]; i1[r] = 1.f / sum1[r]; }
    u16* op0 = O + ((size_t)(b * T) + r0 + quad * 4) * 1024 + h * 64 + l15;
    u16* op1 = O + ((size_t)(b * T) + r1 + quad * 4) * 1024 + h * 64 + l15;
#pragma unroll
    for (int c = 0; c < 4; ++c)
#pragma unroll
      for (int r = 0; r < 4; ++r) {
        op0[(size_t)r * 1024 + c * 16] = f2b(o0[c][r] * i0[r]);
        op1[(size_t)r * 1024 + c * 16] = f2b(o1[c][r] * i1[r]);
      }
  }
}

// ---------------------------------------------------------------------------
// Combine split-K partials: O = (Oa+Ob)/(Sa+Sb), f2b, write Ob.
// grid: 64 bh * 11 qt = 704 blocks of 256 threads; thread handles 1 row-half.
// ---------------------------------------------------------------------------
__global__ __launch_bounds__(256)
void attn_combine(const float* __restrict__ Opart, const float* __restrict__ Spart,
                  u16* __restrict__ O) {
  const int sp = blockIdx.x;                // (bh*11 + qt-5)
  const int bh = sp / 11, qt = 5 + (sp % 11);
  const int b = bh >> 4, h = bh & 15;
  const int t = threadIdx.x;
  const int row = t >> 1, ch = (t & 1) * 32;
  const size_t p0 = (size_t)(2 * sp) * 8192, p1 = p0 + 8192;
  const float s = Spart[(size_t)(2 * sp) * 128 + row] +
                  Spart[(size_t)(2 * sp) * 128 + 128 + row];
  const float inv = 1.f / s;
  const float4* A  = (const float4*)(Opart + p0 + row * 64 + ch);
  const float4* Bv = (const float4*)(Opart + p1 + row * 64 + ch);
  u16* op = O + ((size_t)(b * 2048) + qt * 128 + row) * 1024 + h * 64 + ch;
#pragma unroll
  for (int j = 0; j < 8; ++j) {
    const float4 a = A[j], bb = Bv[j];
    op[j * 4 + 0] = f2b((a.x + bb.x) * inv);
    op[j * 4 + 1] = f2b((a.y + bb.y) * inv);
    op[j * 4 + 2] = f2b((a.z + bb.z) * inv);
    op[j * 4 + 3] = f2b((a.w + bb.w) * inv);
  }
}

// ---------------------------------------------------------------------------
// SwiGLU gate, in-place on fused a13 (M x 8192): first half <- silu(a1)*a3.
// ---------------------------------------------------------------------------
__global__ __launch_bounds__(256) void gate_k(u16* __restrict__ a13) {
  const size_t i = (size_t)blockIdx.x * 256 + threadIdx.x;
  const size_t row = i >> 9, c8 = (i & 511) * 8;
  u16* p1v = a13 + row * 8192 + c8;
  const u16* p3v = p1v + 4096;
  uint4 u1 = *(uint4*)p1v;
  const uint4 u3 = *(const uint4*)p3v;
  u16* p1 = (u16*)&u1;
  const u16* p3 = (const u16*)&u3;
#pragma unroll
  for (int j = 0; j < 8; ++j) {
    const float a = b2f(p1[j]);
    const float g = b2f(p3[j]);
    const float s = a / (1.f + __expf(-a));
    p1[j] = f2b(s * g);
  }
  *(uint4*)p1v = u1;
}

// ---------------------------------------------------------------------------
extern "C" void kernel_launch(void* const* d_in, const int* in_sizes, int n_in,
                              void* d_out, int out_size, void* d_ws, size_t ws_size,
                              hipStream_t stream) {
  const float* x  = (const float*)d_in[0];
  const float* g1 = (const float*)d_in[2];
  const float* wq = (const float*)d_in[3];
  const float* wk = (const float*)d_in[4];
  const float* wv = (const float*)d_in[5];
  const float* wo = (const float*)d_in[6];
  const float* g2 = (const float*)d_in[7];
  const float* w1 = (const float*)d_in[8];
  const float* w2 = (const float*)d_in[9];
  const float* w3 = (const float*)d_in[10];
  float* out = (float*)d_out;

  const int T = 2048, NH = 16, B = 4;
  const int M = B * T;  // 8192
  const size_t MB = 1ull << 20;

  char* ws = (char*)d_ws;
  u16* hb    = (u16*)(ws);              // 16 MB
  u16* wqkvT = (u16*)(ws + 16 * MB);    // 6 MB (3072 x 1024)
  u16* woT   = (u16*)(ws + 22 * MB);    // 2 MB
  u16* w13T  = (u16*)(ws + 24 * MB);    // 16 MB (8192 x 1024: w1T then w3T)
  u16* w2T   = (u16*)(ws + 40 * MB);    // 8 MB (1024 x 4096)
  u16* qkv   = (u16*)(ws + 48 * MB);    // 48 MB (M x 3072)
  u16* VT    = (u16*)(ws + 96 * MB);    // 16 MB (b,h,d,t)
  u16* Ob    = (u16*)(ws + 112 * MB);   // 16 MB
  u16* a13   = (u16*)(ws + 48 * MB);    // 128 MB (M x 8192), overlays qkv/VT/Ob
  // attn split-K partials: live only between attn_kernel and attn_combine;
  // overlay a13's tail (dead during attention). 1408 * 32KB + 1408 * 512B.
  float* Opart = (float*)(ws + 128 * MB);
  float* Spart = Opart + (size_t)1408 * 8192;

  const dim3 tb(32, 8);
  transpose_f2b<<<dim3(32, 32),  tb, 0, stream>>>(wq, wqkvT,              1024, 1024);
  transpose_f2b<<<dim3(32, 32),  tb, 0, stream>>>(wk, wqkvT + 1024*1024,  1024, 1024);
  transpose_f2b<<<dim3(32, 32),  tb, 0, stream>>>(wv, wqkvT + 2048*1024,  1024, 1024);
  transpose_f2b<<<dim3(32, 32),  tb, 0, stream>>>(wo, woT, 1024, 1024);
  transpose_f2b<<<dim3(128, 32), tb, 0, stream>>>(w1, w13T,               1024, 4096);
  transpose_f2b<<<dim3(128, 32), tb, 0, stream>>>(w3, w13T + 4096*1024,   1024, 4096);
  transpose_f2b<<<dim3(32, 128), tb, 0, stream>>>(w2, w2T, 4096, 1024);

  rmsnorm_k<<<M, 256, 0, stream>>>(x, g1, hb);

  // qkv projection: 256^2 2-phase (384 wg)
  gemm256<0><<<dim3(32, 12), 512, 0, stream>>>(hb, wqkvT, qkv, nullptr, M, 3072, 1024, 1024);

  rope_k<<<16384, 256, 0, stream>>>(qkv);
  vtrans_k<<<dim3(64, 128), tb, 0, stream>>>(qkv, VT);

  // attention: split-K (27 (qt,chunk) slots x 64 bh) + combine
  attn_kernel<<<dim3(27, B * NH), 256, 0, stream>>>(qkv, VT, Ob, Opart, Spart);
  attn_combine<<<dim3(704), 256, 0, stream>>>(Opart, Spart, Ob);

  // wo projection: N=1024 -> 256x128 deep-pipelined (256 wg = 1/CU)
  gemm256n<1><<<dim3(32, 8), 512, 0, stream>>>(Ob, woT, out, x, M, 1024, 1024, 1024);

  rmsnorm_k<<<M, 256, 0, stream>>>(out, g2, hb);

  // FFN up (w1|w3): the dominant GEMM -> 256^2 2-phase (1024 wg)
  gemm256<0><<<dim3(32, 32), 512, 0, stream>>>(hb, w13T, a13, nullptr, M, 8192, 1024, 1024);

  gate_k<<<16384, 256, 0, stream>>>(a13);

  // FFN down: N=1024, K=4096 -> 256x128 deep-pipelined (256 wg = 1/CU)
  gemm256n<1><<<dim3(32, 8), 512, 0, stream>>>(a13, w2T, out, out, M, 1024, 4096, 8192);
}

// Round 7
// 635.983 us; speedup vs baseline: 1.0608x; 1.0608x over previous
//
#include <hip/hip_runtime.h>
#include <cstdint>

typedef unsigned short u16;
typedef __attribute__((ext_vector_type(8))) short bf16x8;
typedef __attribute__((ext_vector_type(4))) float f32x4;

__device__ __forceinline__ u16 f2b(float f) {
  union { float f; unsigned u; } c; c.f = f;
  unsigned u = c.u;
  return (u16)((u + 0x7FFFu + ((u >> 16) & 1u)) >> 16);
}
__device__ __forceinline__ float b2f(u16 b) {
  union { unsigned u; float f; } c; c.u = ((unsigned)b) << 16;
  return c.f;
}

typedef __attribute__((address_space(1))) void gv_t;
typedef __attribute__((address_space(3))) void lv_t;
__device__ __forceinline__ void gload_lds16(const void* g, void* l) {
  __builtin_amdgcn_global_load_lds((gv_t*)g, (lv_t*)l, 16, 0, 0);
}

// ---------------------------------------------------------------------------
// Transpose + fp32->bf16 convert: out[c][r] = bf16(in[r][c]); in is R x C.
// block (32,8), grid (C/32, R/32)
// ---------------------------------------------------------------------------
__global__ void transpose_f2b(const float* __restrict__ in, u16* __restrict__ out,
                              int R, int C) {
  __shared__ float t[32][33];
  const int c0 = blockIdx.x * 32, r0 = blockIdx.y * 32;
  const int tx = threadIdx.x, ty = threadIdx.y;
#pragma unroll
  for (int i = 0; i < 4; ++i)
    t[ty + 8 * i][tx] = in[(size_t)(r0 + ty + 8 * i) * C + c0 + tx];
  __syncthreads();
#pragma unroll
  for (int i = 0; i < 4; ++i)
    out[(size_t)(c0 + ty + 8 * i) * R + r0 + tx] = f2b(t[tx][ty + 8 * i]);
}

// ---------------------------------------------------------------------------
// RMSNorm: one row (1024 fp32) per block of 256 threads; bf16 out.
// ---------------------------------------------------------------------------
__global__ __launch_bounds__(256) void rmsnorm_k(const float* __restrict__ x,
                                                 const float* __restrict__ g,
                                                 u16* __restrict__ out) {
  const int row = blockIdx.x, tid = threadIdx.x;
  const float4 v = ((const float4*)x)[(size_t)row * 256 + tid];
  float ss = v.x * v.x + v.y * v.y + v.z * v.z + v.w * v.w;
#pragma unroll
  for (int off = 1; off < 64; off <<= 1) ss += __shfl_xor(ss, off, 64);
  __shared__ float red[4];
  if ((tid & 63) == 0) red[tid >> 6] = ss;
  __syncthreads();
  const float mean = (red[0] + red[1] + red[2] + red[3]) * (1.0f / 1024.0f);
  const float rinv = 1.0f / sqrtf(mean + 1e-6f);
  const float4 gv = ((const float4*)g)[tid];
  u16* o = out + (size_t)row * 1024 + tid * 4;
  o[0] = f2b(v.x * rinv * gv.x);
  o[1] = f2b(v.y * rinv * gv.y);
  o[2] = f2b(v.z * rinv * gv.z);
  o[3] = f2b(v.w * rinv * gv.w);
}

// ---------------------------------------------------------------------------
// RoPE in-place on fused qkv (row stride 3072): rotates q and k halves.
// ---------------------------------------------------------------------------
__global__ __launch_bounds__(256) void rope_k(u16* __restrict__ qkv) {
  const int i = blockIdx.x * 256 + threadIdx.x;   // B*T*NH*32 total
  const int d = i & 31;
  const int h = (i >> 5) & 15;
  const int bt = i >> 9;
  const int t = bt & 2047;
  const float inv = exp2f((float)d * -0.4152410118609203f);  // 10000^(-d/32)
  const float th = (float)t * inv;
  float s, c;
  sincosf(th, &s, &c);
  size_t base = (size_t)bt * 3072 + h * 64 + d;
#pragma unroll
  for (int half = 0; half < 2; ++half) {   // q then k
    const float x1 = b2f(qkv[base]);
    const float x2 = b2f(qkv[base + 32]);
    qkv[base]      = f2b(x1 * c - x2 * s);
    qkv[base + 32] = f2b(x2 * c + x1 * s);
    base += 1024;
  }
}

// ---------------------------------------------------------------------------
// V transpose: qkv (col offset 2048, stride 3072) -> VT (b,h,d,t), u16.
// block (32,8); grid (T/32, 2*B*NH)
// ---------------------------------------------------------------------------
__global__ void vtrans_k(const u16* __restrict__ qkv, u16* __restrict__ VT) {
  __shared__ u16 tl[32][34];
  const int t0 = blockIdx.x * 32;
  const int bh = blockIdx.y >> 1;
  const int d0 = (blockIdx.y & 1) * 32;
  const int b = bh >> 4, h = bh & 15;
  const int tx = threadIdx.x, ty = threadIdx.y;
  const u16* src = qkv + (size_t)(b * 2048 + t0) * 3072 + 2048 + h * 64 + d0;
#pragma unroll
  for (int i = 0; i < 4; ++i)
    tl[ty + 8 * i][tx] = src[(size_t)(ty + 8 * i) * 3072 + tx];
  __syncthreads();
  u16* dst = VT + ((size_t)bh * 64 + d0) * 2048 + t0;
#pragma unroll
  for (int i = 0; i < 4; ++i)
    dst[(size_t)(ty + 8 * i) * 2048 + tx] = tl[tx][ty + 8 * i];
}

// ---------------------------------------------------------------------------
// GEMM 256x256, 2-phase-per-K-tile deep pipeline (round-6, verified).
//   Phase A(t): reads {A0,B0,B1}(t), stages A1(t+1) [2 loads].
//   Phase B(t): reads {A1}(t),       stages {A0,B0,B1}(t+2) [6 loads].
//   vmcnt: uniform vmcnt(8) at steady boundaries; tail A(NT-1)->0, B(NT-2)->2.
//   Requires M%256==0, N%256==0, K%64==0, NT>=2.
// ---------------------------------------------------------------------------
template <int EPI>
__global__ __launch_bounds__(512, 2)
void gemm256(const u16* __restrict__ A, const u16* __restrict__ BT,
             void* __restrict__ Cout, const float* __restrict__ resid,
             int M, int N, int K, int lda) {
  __shared__ alignas(16) u16 LDS[65536];   // 128 KiB: A [0,64K), B [64K,128K)
  char* const ldsc = (char*)LDS;
  const int tid = threadIdx.x;
  const int wave = tid >> 6, lane = tid & 63;
  const int wr = wave >> 2, wc = wave & 3;        // 2 x 4 wave grid
  const int l15 = lane & 15, quad = lane >> 4;
  const int bm = blockIdx.x * 256, bn = blockIdx.y * 256;
  const int NT = K >> 6;                          // 64-wide K tiles

  const int swz = (l15 & 8) << 2;                 // flip byte bit5 when row&8
  const int aoff = (((wr * 64 + l15) * 64 + quad * 16) ^ swz);
  const int boff = (((wc * 32 + l15) * 64 + quad * 16) ^ swz) + 65536;

  const int kperm = ((lane & 3) ^ ((lane >> 5) << 1)) * 8;
  const u16* sA = A + (size_t)(bm + wave * 16 + (lane >> 2)) * lda + kperm;
  const u16* sB = BT + (size_t)(bn + wave * 16 + (lane >> 2)) * K + kperm;
  const size_t hA = (size_t)128 * lda;            // A half-tile row step
  const size_t hB = (size_t)128 * K;              // B half-tile row step
  const int dstW = wave * 1024;                   // linear 1 KiB per wave-load

  f32x4 acc[8][4];
#pragma unroll
  for (int m = 0; m < 8; ++m)
#pragma unroll
    for (int n = 0; n < 4; ++n) acc[m][n] = (f32x4){0.f, 0.f, 0.f, 0.f};
  bf16x8 a[4][2], b[4][2];

  // slot: 0 = A-h0, 1 = B-h0, 2 = A-h1, 3 = B-h1
#define STAGE(kt_, slot_, buf_)                                               \
  if ((kt_) < NT) {                                                           \
    const u16* s_ = (((slot_) & 1) ? sB + ((size_t)((slot_) >> 1)) * hB       \
                                   : sA + ((size_t)((slot_) >> 1)) * hA) +    \
                    (size_t)(kt_) * 64;                                       \
    char* d_ = ldsc + (((slot_) & 1) ? 65536 : 0) + (buf_) * 32768 +          \
               ((slot_) >> 1) * 16384 + dstW;                                 \
    gload_lds16(s_, d_);                                                      \
    gload_lds16(s_ + 32, d_ + 8192);                                          \
  }

#define LOAD_A(mh_, buf_)                                                     \
  _Pragma("unroll") for (int mf = 0; mf < 4; ++mf)                            \
      _Pragma("unroll") for (int kk = 0; kk < 2; ++kk)                        \
          a[mf][kk] = *(const bf16x8*)(ldsc + aoff + (buf_) * 32768 +         \
                                       (mh_) * 16384 + kk * 8192 + mf * 1024);

#define LOAD_B2(buf_)                                                         \
  _Pragma("unroll") for (int nh = 0; nh < 2; ++nh)                            \
      _Pragma("unroll") for (int nf = 0; nf < 2; ++nf)                        \
          _Pragma("unroll") for (int kk = 0; kk < 2; ++kk)                    \
              b[nh * 2 + nf][kk] =                                            \
                  *(const bf16x8*)(ldsc + boff + (buf_) * 32768 +             \
                                   nh * 16384 + kk * 8192 + nf * 1024);

#define MMA2(mh_)                                                             \
  __builtin_amdgcn_s_setprio(1);                                              \
  _Pragma("unroll") for (int mf = 0; mf < 4; ++mf)                            \
      _Pragma("unroll") for (int n = 0; n < 4; ++n)                           \
          _Pragma("unroll") for (int kk = 0; kk < 2; ++kk)                    \
              acc[(mh_) * 4 + mf][n] =                                        \
                  __builtin_amdgcn_mfma_f32_16x16x32_bf16(                    \
                      a[mf][kk], b[n][kk], acc[(mh_) * 4 + mf][n], 0, 0, 0);  \
  __builtin_amdgcn_s_setprio(0);

#define BAR() __builtin_amdgcn_s_barrier()
#define DRAIN_LGKM()                                                          \
  {                                                                           \
    asm volatile("s_waitcnt lgkmcnt(0)" ::: "memory");                        \
    __builtin_amdgcn_sched_barrier(0);                                        \
  }

  // prologue: U(0)={A0,B0,B1}(t0) [6], A1(t0) [2], U(1) [6] -> wait oldest 6
  STAGE(0, 0, 0); STAGE(0, 1, 0); STAGE(0, 3, 0);
  STAGE(0, 2, 0);
  STAGE(1, 0, 1); STAGE(1, 1, 1); STAGE(1, 3, 1);
  asm volatile("s_waitcnt vmcnt(8)" ::: "memory");  // U(0) landed
  BAR();

  for (int t = 0; t < NT; ++t) {
    const int bsel = t & 1;
    // ---- phase A: reads A0(t), B0(t), B1(t) ----
    LOAD_A(0, bsel); LOAD_B2(bsel);
    STAGE(t + 1, 2, bsel ^ 1);                       // A1(t+1)
    BAR(); DRAIN_LGKM(); MMA2(0);
    if (t == NT - 1) { asm volatile("s_waitcnt vmcnt(0)" ::: "memory"); }
    else             { asm volatile("s_waitcnt vmcnt(8)" ::: "memory"); }
    BAR();                                           // A1(t) landed
    // ---- phase B: reads A1(t) ----
    LOAD_A(1, bsel);
    STAGE(t + 2, 0, bsel); STAGE(t + 2, 1, bsel); STAGE(t + 2, 3, bsel);
    BAR(); DRAIN_LGKM(); MMA2(1);
    if (t < NT - 2) {
      asm volatile("s_waitcnt vmcnt(8)" ::: "memory");
      BAR();                                         // U(t+1) landed
    } else if (t == NT - 2) {
      asm volatile("s_waitcnt vmcnt(2)" ::: "memory");
      BAR();
    }
    // t == NT-1: fall through to epilogue (no LDS reads follow)
  }
#undef STAGE
#undef LOAD_A
#undef LOAD_B2
#undef MMA2

  // epilogue: C/D layout col=lane&15, row=(lane>>4)*4+reg
#pragma unroll
  for (int m = 0; m < 8; ++m) {
    const int gr = bm + (m >> 2) * 128 + wr * 64 + (m & 3) * 16 + quad * 4;
#pragma unroll
    for (int n = 0; n < 4; ++n) {
      const int gc = bn + (n >> 1) * 128 + wc * 32 + (n & 1) * 16 + l15;
#pragma unroll
      for (int r = 0; r < 4; ++r) {
        const size_t off = (size_t)(gr + r) * N + gc;
        if (EPI == 0) {
          ((u16*)Cout)[off] = f2b(acc[m][n][r]);
        } else {
          ((float*)Cout)[off] = resid[off] + acc[m][n][r];
        }
      }
    }
  }
#undef BAR
#undef DRAIN_LGKM
}

// ---------------------------------------------------------------------------
// GEMM 256x128 DUAL-B + fused SwiGLU gate (w13). Same verified 2-phase
// schedule/ledger as gemm256 v2 with slots {A0,A1,B0,B1}->{A0,A1,B1,B3}:
// B1 from w1T col-tile, B3 from w3T col-tile (same 128 output cols), A staged
// once and shared. Epilogue: out = bf16(silu(c1) * c3) on fp32 accumulators
// (closer to the fp32 reference than the old bf16-roundtrip + gate_k pass).
// Per-tile stage ops = 8 (A1:2 in phase A; A0,B1,B3:6 in phase B) -> the
// vmcnt(8)/tail(2,0) ledger carries over unchanged. LDS 128 KiB:
// A [0,64K) = [buf 32K][half 16K]; B1 65536+[buf 16K]; B3 98304+[buf 16K].
// grid (M/256, Ncols/128). Requires K%64==0, NT>=2.
// ---------------------------------------------------------------------------
__global__ __launch_bounds__(512, 2)
void gemm256g(const u16* __restrict__ A, const u16* __restrict__ B1T,
              const u16* __restrict__ B3T, u16* __restrict__ Cout,
              int Ncols, int K, int lda) {
  __shared__ alignas(16) u16 LDS[65536];
  char* const ldsc = (char*)LDS;
  const int tid = threadIdx.x;
  const int wave = tid >> 6, lane = tid & 63;
  const int wr = wave >> 2, wc = wave & 3;
  const int l15 = lane & 15, quad = lane >> 4;
  const int bm = blockIdx.x * 256, bn = blockIdx.y * 128;
  const int NT = K >> 6;

  const int swz = (l15 & 8) << 2;
  const int aoff  = (((wr * 64 + l15) * 64 + quad * 16) ^ swz);
  const int b1off = (((wc * 32 + l15) * 64 + quad * 16) ^ swz) + 65536;

  const int kperm = ((lane & 3) ^ ((lane >> 5) << 1)) * 8;
  const u16* sA  = A   + (size_t)(bm + wave * 16 + (lane >> 2)) * lda + kperm;
  const u16* sB1 = B1T + (size_t)(bn + wave * 16 + (lane >> 2)) * K + kperm;
  const u16* sB3 = B3T + (size_t)(bn + wave * 16 + (lane >> 2)) * K + kperm;
  const size_t hA = (size_t)128 * lda;
  const int dstW = wave * 1024;

  f32x4 acc1[8][2], acc3[8][2];
#pragma unroll
  for (int m = 0; m < 8; ++m)
#pragma unroll
    for (int n = 0; n < 2; ++n) {
      acc1[m][n] = (f32x4){0.f, 0.f, 0.f, 0.f};
      acc3[m][n] = (f32x4){0.f, 0.f, 0.f, 0.f};
    }
  bf16x8 a[4][2], b1[2][2], b3[2][2];

#define STAGE_A(kt_, half_, buf_)                                             \
  if ((kt_) < NT) {                                                           \
    const u16* s_ = sA + (size_t)(half_) * hA + (size_t)(kt_) * 64;           \
    char* d_ = ldsc + (buf_) * 32768 + (half_) * 16384 + dstW;                \
    gload_lds16(s_, d_);                                                      \
    gload_lds16(s_ + 32, d_ + 8192);                                          \
  }
#define STAGE_B1(kt_, buf_)                                                   \
  if ((kt_) < NT) {                                                           \
    const u16* s_ = sB1 + (size_t)(kt_) * 64;                                 \
    char* d_ = ldsc + 65536 + (buf_) * 16384 + dstW;                          \
    gload_lds16(s_, d_);                                                      \
    gload_lds16(s_ + 32, d_ + 8192);                                          \
  }
#define STAGE_B3(kt_, buf_)                                                   \
  if ((kt_) < NT) {                                                           \
    const u16* s_ = sB3 + (size_t)(kt_) * 64;                                 \
    char* d_ = ldsc + 98304 + (buf_) * 16384 + dstW;                          \
    gload_lds16(s_, d_);                                                      \
    gload_lds16(s_ + 32, d_ + 8192);                                          \
  }
#define LOAD_A(mh_, buf_)                                                     \
  _Pragma("unroll") for (int mf = 0; mf < 4; ++mf)                            \
      _Pragma("unroll") for (int kk = 0; kk < 2; ++kk)                        \
          a[mf][kk] = *(const bf16x8*)(ldsc + aoff + (buf_) * 32768 +         \
                                       (mh_) * 16384 + kk * 8192 + mf * 1024);
#define LOAD_B13(buf_)                                                        \
  _Pragma("unroll") for (int nf = 0; nf < 2; ++nf)                            \
      _Pragma("unroll") for (int kk = 0; kk < 2; ++kk) {                      \
        b1[nf][kk] = *(const bf16x8*)(ldsc + b1off + (buf_) * 16384 +         \
                                      kk * 8192 + nf * 1024);                 \
        b3[nf][kk] = *(const bf16x8*)(ldsc + b1off + 32768 +                  \
                                      (buf_) * 16384 + kk * 8192 +            \
                                      nf * 1024);                             \
      }
#define MMAG(mh_)                                                             \
  __builtin_amdgcn_s_setprio(1);                                              \
  _Pragma("unroll") for (int mf = 0; mf < 4; ++mf)                            \
      _Pragma("unroll") for (int nf = 0; nf < 2; ++nf)                        \
          _Pragma("unroll") for (int kk = 0; kk < 2; ++kk) {                  \
            acc1[(mh_) * 4 + mf][nf] =                                        \
                __builtin_amdgcn_mfma_f32_16x16x32_bf16(                      \
                    a[mf][kk], b1[nf][kk], acc1[(mh_) * 4 + mf][nf], 0, 0, 0);\
            acc3[(mh_) * 4 + mf][nf] =                                        \
                __builtin_amdgcn_mfma_f32_16x16x32_bf16(                      \
                    a[mf][kk], b3[nf][kk], acc3[(mh_) * 4 + mf][nf], 0, 0, 0);\
          }                                                                   \
  __builtin_amdgcn_s_setprio(0);
#define BAR() __builtin_amdgcn_s_barrier()
#define DRAIN_LGKM()                                                          \
  {                                                                           \
    asm volatile("s_waitcnt lgkmcnt(0)" ::: "memory");                        \
    __builtin_amdgcn_sched_barrier(0);                                        \
  }

  // prologue: U(0)={A0,B1,B3}(t0) [6], A1(t0) [2], U(1) [6]
  STAGE_A(0, 0, 0); STAGE_B1(0, 0); STAGE_B3(0, 0);
  STAGE_A(0, 1, 0);
  STAGE_A(1, 0, 1); STAGE_B1(1, 1); STAGE_B3(1, 1);
  asm volatile("s_waitcnt vmcnt(8)" ::: "memory");  // U(0) landed
  BAR();

  for (int t = 0; t < NT; ++t) {
    const int bsel = t & 1;
    // ---- phase A: reads A0(t), B1(t), B3(t) ----
    LOAD_A(0, bsel); LOAD_B13(bsel);
    STAGE_A(t + 1, 1, bsel ^ 1);                     // A1(t+1)
    BAR(); DRAIN_LGKM(); MMAG(0);
    if (t == NT - 1) { asm volatile("s_waitcnt vmcnt(0)" ::: "memory"); }
    else             { asm volatile("s_waitcnt vmcnt(8)" ::: "memory"); }
    BAR();                                           // A1(t) landed
    // ---- phase B: reads A1(t) ----
    LOAD_A(1, bsel);
    STAGE_A(t + 2, 0, bsel); STAGE_B1(t + 2, bsel); STAGE_B3(t + 2, bsel);
    BAR(); DRAIN_LGKM(); MMAG(1);
    if (t < NT - 2) {
      asm volatile("s_waitcnt vmcnt(8)" ::: "memory");
      BAR();
    } else if (t == NT - 2) {
      asm volatile("s_waitcnt vmcnt(2)" ::: "memory");
      BAR();
    }
  }
#undef STAGE_A
#undef STAGE_B1
#undef STAGE_B3
#undef LOAD_A
#undef LOAD_B13
#undef MMAG
#undef BAR
#undef DRAIN_LGKM

  // epilogue: gated store, out[gr][gc] = bf16(silu(c1)*c3)
#pragma unroll
  for (int m = 0; m < 8; ++m) {
    const int gr = bm + (m >> 2) * 128 + wr * 64 + (m & 3) * 16 + quad * 4;
#pragma unroll
    for (int n = 0; n < 2; ++n) {
      const int gc = bn + wc * 32 + n * 16 + l15;
#pragma unroll
      for (int r = 0; r < 4; ++r) {
        const float v1 = acc1[m][n][r];
        const float v3 = acc3[m][n][r];
        const float s = v1 / (1.f + __expf(-v1));
        Cout[(size_t)(gr + r) * Ncols + gc] = f2b(s * v3);
      }
    }
  }
}

// ---------------------------------------------------------------------------
// GEMM 256x128 deep-pipelined (for N=1024: 256 wg = 1/CU). See round-3 notes.
// Requires M%256==0, N%128==0, K%64==0, NT>=3.
// ---------------------------------------------------------------------------
template <int EPI>
__global__ __launch_bounds__(512, 2)
void gemm256n(const u16* __restrict__ A, const u16* __restrict__ BT,
              void* __restrict__ Cout, const float* __restrict__ resid,
              int M, int N, int K, int lda) {
  __shared__ alignas(16) u16 LDS[49152];   // 96 KiB: A [0,64K), B [64K,96K)
  char* const ldsc = (char*)LDS;
  const int tid = threadIdx.x;
  const int wave = tid >> 6, lane = tid & 63;
  const int wr = wave >> 2, wc = wave & 3;        // 2 x 4 wave grid
  const int l15 = lane & 15, quad = lane >> 4;
  const int bm = blockIdx.x * 256, bn = blockIdx.y * 128;
  const int NT = K >> 6;

  // swizzled per-lane ds-read byte offsets (st_16x32: flip byte bit5 on row&8)
  const int swz = (l15 & 8) << 2;
  const int aoff = (((wr * 64 + l15) * 64 + quad * 16) ^ swz);
  const int boff = (((wc * 32 + l15) * 64 + quad * 16) ^ swz) + 65536;

  // staging: per-lane global source, k-position inverse-swizzled
  const int kperm = ((lane & 3) ^ ((lane >> 5) << 1)) * 8;
  const u16* sA = A + (size_t)(bm + wave * 16 + (lane >> 2)) * lda + kperm;
  const u16* sB = BT + (size_t)(bn + wave * 16 + (lane >> 2)) * K + kperm;
  const size_t hA = (size_t)128 * lda;            // A half-tile row step
  const int dstW = wave * 1024;

  f32x4 acc[8][2];
#pragma unroll
  for (int m = 0; m < 8; ++m)
#pragma unroll
    for (int n = 0; n < 2; ++n) acc[m][n] = (f32x4){0.f, 0.f, 0.f, 0.f};
  bf16x8 a[4][2], b[2][2];

  // A layout: [buf:32768][half:16384][kk:8192][128 rows x 64B]
  // B layout: 65536 + [buf:16384][kk:8192][128 rows x 64B]
#define STAGE_A(kt_, half_, buf_)                                             \
  if ((kt_) < NT) {                                                           \
    const u16* s_ = sA + (size_t)(half_) * hA + (size_t)(kt_) * 64;           \
    char* d_ = ldsc + (buf_) * 32768 + (half_) * 16384 + dstW;                \
    gload_lds16(s_, d_);                                                      \
    gload_lds16(s_ + 32, d_ + 8192);                                          \
  }
#define STAGE_B(kt_, buf_)                                                    \
  if ((kt_) < NT) {                                                           \
    const u16* s_ = sB + (size_t)(kt_) * 64;                                  \
    char* d_ = ldsc + 65536 + (buf_) * 16384 + dstW;                          \
    gload_lds16(s_, d_);                                                      \
    gload_lds16(s_ + 32, d_ + 8192);                                          \
  }
#define LOAD_A(mh_, buf_)                                                     \
  _Pragma("unroll") for (int mf = 0; mf < 4; ++mf)                            \
      _Pragma("unroll") for (int kk = 0; kk < 2; ++kk)                        \
          a[mf][kk] = *(const bf16x8*)(ldsc + aoff + (buf_) * 32768 +         \
                                       (mh_) * 16384 + kk * 8192 + mf * 1024);
#define LOAD_B(buf_)                                                          \
  _Pragma("unroll") for (int nf = 0; nf < 2; ++nf)                            \
      _Pragma("unroll") for (int kk = 0; kk < 2; ++kk)                        \
          b[nf][kk] = *(const bf16x8*)(ldsc + boff + (buf_) * 16384 +         \
                                       kk * 8192 + nf * 1024);
#define MMA(mh_)                                                              \
  __builtin_amdgcn_s_setprio(1);                                              \
  _Pragma("unroll") for (int mf = 0; mf < 4; ++mf)                            \
      _Pragma("unroll") for (int nf = 0; nf < 2; ++nf)                        \
          _Pragma("unroll") for (int kk = 0; kk < 2; ++kk)                    \
              acc[(mh_) * 4 + mf][nf] =                                       \
                  __builtin_amdgcn_mfma_f32_16x16x32_bf16(                    \
                      a[mf][kk], b[nf][kk], acc[(mh_) * 4 + mf][nf], 0, 0, 0);\
  __builtin_amdgcn_s_setprio(0);
#define BAR() __builtin_amdgcn_s_barrier()
#define DRAIN_LGKM()                                                          \
  {                                                                           \
    asm volatile("s_waitcnt lgkmcnt(0)" ::: "memory");                        \
    __builtin_amdgcn_sched_barrier(0);                                        \
  }

  // prologue (issue order defines the vmcnt ledger!)
  STAGE_A(0, 0, 0); STAGE_B(0, 0);   // t0.A0B  (4)
  STAGE_A(0, 1, 0);                  // t0.A1   (2)
  STAGE_A(1, 0, 1); STAGE_B(1, 1);   // t1.A0B  (4)
  asm volatile("s_waitcnt vmcnt(6)" ::: "memory");   // t0.A0B landed
  BAR();

  for (int t = 0; t < NT; ++t) {
    const int bsel = t & 1;
    // ---- phase 0: reads A0(t), B(t) ----
    LOAD_A(0, bsel); LOAD_B(bsel);
    STAGE_A(t + 1, 1, bsel ^ 1);                     // (t+1).A1
    BAR(); DRAIN_LGKM(); MMA(0);
    if (t == NT - 1) { asm volatile("s_waitcnt vmcnt(0)" ::: "memory"); }
    else             { asm volatile("s_waitcnt vmcnt(6)" ::: "memory"); }
    BAR();                                           // A1(t) landed
    // ---- phase 1: reads A1(t) ----
    LOAD_A(1, bsel);
    STAGE_A(t + 2, 0, bsel); STAGE_B(t + 2, bsel);   // (t+2).A0B
    BAR(); DRAIN_LGKM(); MMA(1);
    if (t == NT - 2)     { asm volatile("s_waitcnt vmcnt(2)" ::: "memory"); }
    else if (t < NT - 2) { asm volatile("s_waitcnt vmcnt(6)" ::: "memory"); }
    BAR();                                           // A0B(t+1) landed
  }
#undef STAGE_A
#undef STAGE_B
#undef LOAD_A
#undef LOAD_B
#undef MMA
#undef BAR
#undef DRAIN_LGKM

  // epilogue: C/D layout col=lane&15, row=(lane>>4)*4+reg
#pragma unroll
  for (int m = 0; m < 8; ++m) {
    const int gr = bm + (m >> 2) * 128 + wr * 64 + (m & 3) * 16 + quad * 4;
#pragma unroll
    for (int n = 0; n < 2; ++n) {
      const int gc = bn + wc * 32 + n * 16 + l15;
#pragma unroll
      for (int r = 0; r < 4; ++r) {
        const size_t off = (size_t)(gr + r) * N + gc;
        if (EPI == 0) {
          ((u16*)Cout)[off] = f2b(acc[m][n][r]);
        } else {
          ((float*)Cout)[off] = resid[off] + acc[m][n][r];
        }
      }
    }
  }
}

// ---------------------------------------------------------------------------
// Causal flash attention v6 = split-K over the key range (round-4, verified).
// Fixed-bias softmax -> K-tile contributions are order-independent sums, so
// a q-tile's K range splits EXACTLY across blocks: O = (Oa+Ob)/(Sa+Sb).
// ---------------------------------------------------------------------------
__global__ __launch_bounds__(256)
void attn_kernel(const u16* __restrict__ QKV, const u16* __restrict__ VT,
                 u16* __restrict__ O, float* __restrict__ Opart,
                 float* __restrict__ Spart) {
  const int T = 2048, stQ = 3072;
  const int tid = threadIdx.x, wave = tid >> 6, lane = tid & 63;
  const int l15 = lane & 15, quad = lane >> 4;

  // (qt, chunk) from the 27-slot LPT table
  const int xi = (int)blockIdx.x;
  const bool split = (xi < 22);
  const int qt = split ? (15 - (xi >> 1)) : (26 - xi);
  const int chunk = split ? (xi & 1) : 0;
  const int len = split ? (qt + 1) : (2 * qt + 2);   // tiles this block
  const int kt0 = chunk * (qt + 1);
  const int ktEnd = kt0 + len;

  const int qb0 = qt * 128;
  const int bh = blockIdx.y, b = bh >> 4, h = bh & 15;
  const float sc2 = 0.125f * 1.44269504088896f;   // scale * log2(e)
  const float M0 = 32.0f;                         // fixed softmax bias

  __shared__ alignas(16) u16 Kf[2][8 * 512];  // dbuf, fragment-major
  __shared__ alignas(16) u16 Vf[2][8 * 512];
  __shared__ alignas(16) u16 Pl[4][2][16 * 72];

  const u16* Qb  = QKV + (size_t)b * T * stQ + h * 64;
  const u16* Kb  = Qb + 1024;
  const u16* VTb = VT + (size_t)bh * 64 * T;

  const int r0 = qb0 + wave * 16;   // frag0 wave rows
  const int r1 = r0 + 64;           // frag1 wave rows (always causally active)
  const u16* qp0 = Qb + (size_t)(r0 + l15) * stQ + quad * 8;
  const u16* qp1 = Qb + (size_t)(r1 + l15) * stQ + quad * 8;
  const bf16x8 qf00 = *(const bf16x8*)qp0;
  const bf16x8 qf01 = *(const bf16x8*)(qp0 + 32);
  const bf16x8 qf10 = *(const bf16x8*)qp1;
  const bf16x8 qf11 = *(const bf16x8*)(qp1 + 32);

  bf16x8 ones;
#pragma unroll
  for (int j = 0; j < 8; ++j) ones[j] = (short)0x3F80;   // bf16 1.0

  // staging sources (lane-permuted so LDS lands fragment-major)
  const u16* kS = Kb + (size_t)(wave * 16 + l15) * stQ + quad * 8;
  const u16* vS = VTb + (size_t)(wave * 16 + l15) * T + quad * 8;

  f32x4 o0[4], o1[4], sum0, sum1;
#pragma unroll
  for (int c = 0; c < 4; ++c) {
    o0[c] = (f32x4){0.f, 0.f, 0.f, 0.f};
    o1[c] = (f32x4){0.f, 0.f, 0.f, 0.f};
  }
  sum0 = (f32x4){0.f, 0.f, 0.f, 0.f};
  sum1 = (f32x4){0.f, 0.f, 0.f, 0.f};

  u16* pw0 = &Pl[wave][0][0];
  u16* pw1 = &Pl[wave][1][0];

  // prologue: stage tile kt0 into buf 0
  gload_lds16(kS + (size_t)(kt0 * 64) * stQ,      &Kf[0][(wave * 2 + 0) * 512]);
  gload_lds16(kS + (size_t)(kt0 * 64) * stQ + 32, &Kf[0][(wave * 2 + 1) * 512]);
  gload_lds16(vS + (size_t)(kt0 * 64),            &Vf[0][(wave * 2 + 0) * 512]);
  gload_lds16(vS + (size_t)(kt0 * 64) + 32,       &Vf[0][(wave * 2 + 1) * 512]);

  for (int kt = kt0; kt < ktEnd; ++kt) {
    const int kb0 = kt * 64;
    const int buf = (kt - kt0) & 1;
    __builtin_amdgcn_sched_barrier(0);   // keep stage below prev trailing bar
    if (kt + 1 < ktEnd) {
      const size_t kb1 = (size_t)(kb0 + 64);
      gload_lds16(kS + kb1 * stQ,      &Kf[buf ^ 1][(wave * 2 + 0) * 512]);
      gload_lds16(kS + kb1 * stQ + 32, &Kf[buf ^ 1][(wave * 2 + 1) * 512]);
      gload_lds16(vS + kb1,            &Vf[buf ^ 1][(wave * 2 + 0) * 512]);
      gload_lds16(vS + kb1 + 32,       &Vf[buf ^ 1][(wave * 2 + 1) * 512]);
      asm volatile("s_waitcnt vmcnt(4)" ::: "memory");  // tile kt landed
    } else {
      asm volatile("s_waitcnt vmcnt(0)" ::: "memory");
    }
    __builtin_amdgcn_s_barrier();        // cross-wave visibility of tile kt
    __builtin_amdgcn_sched_barrier(0);   // keep LDS reads below barrier

    bf16x8 kf[8], vf[8];
#pragma unroll
    for (int g = 0; g < 8; ++g) {
      kf[g] = *(const bf16x8*)(&Kf[buf][g * 512 + lane * 8]);
      vf[g] = *(const bf16x8*)(&Vf[buf][g * 512 + lane * 8]);
    }

    const bool act0 = (kb0 <= r0 + 15);   // wave-uniform causal tile skip

    // ---- frag1 (always active): S -> P(bf16, LDS) ----
    {
      f32x4 s[4];
      __builtin_amdgcn_s_setprio(1);
#pragma unroll
      for (int jj = 0; jj < 4; ++jj) {
        s[jj] = (f32x4){0.f, 0.f, 0.f, 0.f};
        s[jj] = __builtin_amdgcn_mfma_f32_16x16x32_bf16(qf10, kf[jj * 2 + 0], s[jj], 0, 0, 0);
        s[jj] = __builtin_amdgcn_mfma_f32_16x16x32_bf16(qf11, kf[jj * 2 + 1], s[jj], 0, 0, 0);
      }
      __builtin_amdgcn_s_setprio(0);
      if (kb0 + 63 > r1) {   // diagonal-crossing tile
#pragma unroll
        for (int jj = 0; jj < 4; ++jj)
#pragma unroll
          for (int r = 0; r < 4; ++r) {
            const bool msk = (kb0 + jj * 16 + l15) > (r1 + quad * 4 + r);
            const float a = msk ? -1e30f : (s[jj][r] * sc2 - M0);
            pw1[(quad * 4 + r) * 72 + jj * 16 + l15] = f2b(exp2f(a));
          }
      } else {
#pragma unroll
        for (int jj = 0; jj < 4; ++jj)
#pragma unroll
          for (int r = 0; r < 4; ++r)
            pw1[(quad * 4 + r) * 72 + jj * 16 + l15] =
                f2b(exp2f(s[jj][r] * sc2 - M0));
      }
    }
    // ---- frag0 (skippable) ----
    if (act0) {
      f32x4 s[4];
      __builtin_amdgcn_s_setprio(1);
#pragma unroll
      for (int jj = 0; jj < 4; ++jj) {
        s[jj] = (f32x4){0.f, 0.f, 0.f, 0.f};
        s[jj] = __builtin_amdgcn_mfma_f32_16x16x32_bf16(qf00, kf[jj * 2 + 0], s[jj], 0, 0, 0);
        s[jj] = __builtin_amdgcn_mfma_f32_16x16x32_bf16(qf01, kf[jj * 2 + 1], s[jj], 0, 0, 0);
      }
      __builtin_amdgcn_s_setprio(0);
      if (kb0 + 63 > r0) {
#pragma unroll
        for (int jj = 0; jj < 4; ++jj)
#pragma unroll
          for (int r = 0; r < 4; ++r) {
            const bool msk = (kb0 + jj * 16 + l15) > (r0 + quad * 4 + r);
            const float a = msk ? -1e30f : (s[jj][r] * sc2 - M0);
            pw0[(quad * 4 + r) * 72 + jj * 16 + l15] = f2b(exp2f(a));
          }
      } else {
#pragma unroll
        for (int jj = 0; jj < 4; ++jj)
#pragma unroll
          for (int r = 0; r < 4; ++r)
            pw0[(quad * 4 + r) * 72 + jj * 16 + l15] =
                f2b(exp2f(s[jj][r] * sc2 - M0));
      }
    }

    // ---- PV + row sums (no rescale needed: fixed bias) ----
    const bf16x8 pf10 = *(const bf16x8*)(pw1 + l15 * 72 + quad * 8);
    const bf16x8 pf11 = *(const bf16x8*)(pw1 + l15 * 72 + 32 + quad * 8);
    __builtin_amdgcn_s_setprio(1);
#pragma unroll
    for (int c = 0; c < 4; ++c) {
      o1[c] = __builtin_amdgcn_mfma_f32_16x16x32_bf16(pf10, vf[c * 2 + 0], o1[c], 0, 0, 0);
      o1[c] = __builtin_amdgcn_mfma_f32_16x16x32_bf16(pf11, vf[c * 2 + 1], o1[c], 0, 0, 0);
    }
    sum1 = __builtin_amdgcn_mfma_f32_16x16x32_bf16(pf10, ones, sum1, 0, 0, 0);
    sum1 = __builtin_amdgcn_mfma_f32_16x16x32_bf16(pf11, ones, sum1, 0, 0, 0);
    __builtin_amdgcn_s_setprio(0);
    if (act0) {
      const bf16x8 pf00 = *(const bf16x8*)(pw0 + l15 * 72 + quad * 8);
      const bf16x8 pf01 = *(const bf16x8*)(pw0 + l15 * 72 + 32 + quad * 8);
      __builtin_amdgcn_s_setprio(1);
#pragma unroll
      for (int c = 0; c < 4; ++c) {
        o0[c] = __builtin_amdgcn_mfma_f32_16x16x32_bf16(pf00, vf[c * 2 + 0], o0[c], 0, 0, 0);
        o0[c] = __builtin_amdgcn_mfma_f32_16x16x32_bf16(pf01, vf[c * 2 + 1], o0[c], 0, 0, 0);
      }
      sum0 = __builtin_amdgcn_mfma_f32_16x16x32_bf16(pf00, ones, sum0, 0, 0, 0);
      sum0 = __builtin_amdgcn_mfma_f32_16x16x32_bf16(pf01, ones, sum0, 0, 0, 0);
      __builtin_amdgcn_s_setprio(0);
    }
    __builtin_amdgcn_s_barrier();        // all waves done reading buf
  }

  if (split) {
    // fp32 partials: Opart[pi][128 rows][64 cols], Spart[pi][128 rows]
    const int pi = (bh * 11 + (qt - 5)) * 2 + chunk;
    float* Po = Opart + (size_t)pi * 8192;
    float* Ps = Spart + (size_t)pi * 128;
    const int lr0 = wave * 16 + quad * 4;     // frag0 local row base
#pragma unroll
    for (int c = 0; c < 4; ++c)
#pragma unroll
      for (int r = 0; r < 4; ++r) {
        Po[(lr0 + r) * 64 + c * 16 + l15]      = o0[c][r];
        Po[(64 + lr0 + r) * 64 + c * 16 + l15] = o1[c][r];
      }
    if (l15 == 0) {
#pragma unroll
      for (int r = 0; r < 4; ++r) {
        Ps[lr0 + r]      = sum0[r];
        Ps[64 + lr0 + r] = sum1[r];
      }
    }
  } else {
    float i0[4], i1[4];
#pragma unroll
    for (int r = 0; r < 4; ++r) { i0[r] = 1.f / sum0[r]; i1[r] = 1.f / sum1[r]; }
    u16* op0 = O + ((size_t)(b * T) + r0 + quad * 4) * 1024 + h * 64 + l15;
    u16* op1 = O + ((size_t)(b * T) + r1 + quad * 4) * 1024 + h * 64 + l15;
#pragma unroll
    for (int c = 0; c < 4; ++c)
#pragma unroll
      for (int r = 0; r < 4; ++r) {
        op0[(size_t)r * 1024 + c * 16] = f2b(o0[c][r] * i0[r]);
        op1[(size_t)r * 1024 + c * 16] = f2b(o1[c][r] * i1[r]);
      }
  }
}

// ---------------------------------------------------------------------------
// Combine split-K partials: O = (Oa+Ob)/(Sa+Sb), f2b, write Ob.
// grid: 64 bh * 11 qt = 704 blocks of 256 threads; thread handles 1 row-half.
// ---------------------------------------------------------------------------
__global__ __launch_bounds__(256)
void attn_combine(const float* __restrict__ Opart, const float* __restrict__ Spart,
                  u16* __restrict__ O) {
  const int sp = blockIdx.x;                // (bh*11 + qt-5)
  const int bh = sp / 11, qt = 5 + (sp % 11);
  const int b = bh >> 4, h = bh & 15;
  const int t = threadIdx.x;
  const int row = t >> 1, ch = (t & 1) * 32;
  const size_t p0 = (size_t)(2 * sp) * 8192, p1 = p0 + 8192;
  const float s = Spart[(size_t)(2 * sp) * 128 + row] +
                  Spart[(size_t)(2 * sp) * 128 + 128 + row];
  const float inv = 1.f / s;
  const float4* A  = (const float4*)(Opart + p0 + row * 64 + ch);
  const float4* Bv = (const float4*)(Opart + p1 + row * 64 + ch);
  u16* op = O + ((size_t)(b * 2048) + qt * 128 + row) * 1024 + h * 64 + ch;
#pragma unroll
  for (int j = 0; j < 8; ++j) {
    const float4 a = A[j], bb = Bv[j];
    op[j * 4 + 0] = f2b((a.x + bb.x) * inv);
    op[j * 4 + 1] = f2b((a.y + bb.y) * inv);
    op[j * 4 + 2] = f2b((a.z + bb.z) * inv);
    op[j * 4 + 3] = f2b((a.w + bb.w) * inv);
  }
}

// ---------------------------------------------------------------------------
extern "C" void kernel_launch(void* const* d_in, const int* in_sizes, int n_in,
                              void* d_out, int out_size, void* d_ws, size_t ws_size,
                              hipStream_t stream) {
  const float* x  = (const float*)d_in[0];
  const float* g1 = (const float*)d_in[2];
  const float* wq = (const float*)d_in[3];
  const float* wk = (const float*)d_in[4];
  const float* wv = (const float*)d_in[5];
  const float* wo = (const float*)d_in[6];
  const float* g2 = (const float*)d_in[7];
  const float* w1 = (const float*)d_in[8];
  const float* w2 = (const float*)d_in[9];
  const float* w3 = (const float*)d_in[10];
  float* out = (float*)d_out;

  const int T = 2048, NH = 16, B = 4;
  const int M = B * T;  // 8192
  const size_t MB = 1ull << 20;

  char* ws = (char*)d_ws;
  u16* hb    = (u16*)(ws);              // 16 MB
  u16* wqkvT = (u16*)(ws + 16 * MB);    // 6 MB (3072 x 1024)
  u16* woT   = (u16*)(ws + 22 * MB);    // 2 MB
  u16* w13T  = (u16*)(ws + 24 * MB);    // 16 MB (8192 x 1024: w1T then w3T)
  u16* w2T   = (u16*)(ws + 40 * MB);    // 8 MB (1024 x 4096)
  u16* qkv   = (u16*)(ws + 48 * MB);    // 48 MB (M x 3072)
  u16* VT    = (u16*)(ws + 96 * MB);    // 16 MB (b,h,d,t)
  u16* Ob    = (u16*)(ws + 112 * MB);   // 16 MB
  u16* a13g  = (u16*)(ws + 48 * MB);    // 64 MB (M x 4096 gated), overlays qkv/VT
  // attn split-K partials: live only between attn_kernel and attn_combine;
  // overlay dead region. 1408 * 32KB + 1408 * 512B.
  float* Opart = (float*)(ws + 128 * MB);
  float* Spart = Opart + (size_t)1408 * 8192;

  const dim3 tb(32, 8);
  transpose_f2b<<<dim3(32, 32),  tb, 0, stream>>>(wq, wqkvT,              1024, 1024);
  transpose_f2b<<<dim3(32, 32),  tb, 0, stream>>>(wk, wqkvT + 1024*1024,  1024, 1024);
  transpose_f2b<<<dim3(32, 32),  tb, 0, stream>>>(wv, wqkvT + 2048*1024,  1024, 1024);
  transpose_f2b<<<dim3(32, 32),  tb, 0, stream>>>(wo, woT, 1024, 1024);
  transpose_f2b<<<dim3(128, 32), tb, 0, stream>>>(w1, w13T,               1024, 4096);
  transpose_f2b<<<dim3(128, 32), tb, 0, stream>>>(w3, w13T + 4096*1024,   1024, 4096);
  transpose_f2b<<<dim3(32, 128), tb, 0, stream>>>(w2, w2T, 4096, 1024);

  rmsnorm_k<<<M, 256, 0, stream>>>(x, g1, hb);

  // qkv projection: 256^2 2-phase (384 wg)
  gemm256<0><<<dim3(32, 12), 512, 0, stream>>>(hb, wqkvT, qkv, nullptr, M, 3072, 1024, 1024);

  rope_k<<<16384, 256, 0, stream>>>(qkv);
  vtrans_k<<<dim3(64, 128), tb, 0, stream>>>(qkv, VT);

  // attention: split-K (27 (qt,chunk) slots x 64 bh) + combine
  attn_kernel<<<dim3(27, B * NH), 256, 0, stream>>>(qkv, VT, Ob, Opart, Spart);
  attn_combine<<<dim3(704), 256, 0, stream>>>(Opart, Spart, Ob);

  // wo projection: N=1024 -> 256x128 deep-pipelined (256 wg = 1/CU)
  gemm256n<1><<<dim3(32, 8), 512, 0, stream>>>(Ob, woT, out, x, M, 1024, 1024, 1024);

  rmsnorm_k<<<M, 256, 0, stream>>>(out, g2, hb);

  // FFN up + fused SwiGLU gate: dual-B (w1T, w3T), writes gated M x 4096
  gemm256g<<<dim3(32, 32), 512, 0, stream>>>(hb, w13T, w13T + (size_t)4096 * 1024,
                                             a13g, 4096, 1024, 1024);

  // FFN down: N=1024, K=4096, lda now 4096 (compact gated activations)
  gemm256n<1><<<dim3(32, 8), 512, 0, stream>>>(a13g, w2T, out, out, M, 1024, 4096, 4096);
}